// Round 11
// baseline (14.069 us; speedup 1.0000x reference)
//
#include <hip/hip_runtime.h>
#include <math.h>

// ---- problem constants ----
// SIZE=(60,270,480); CHANNELS=14; GRIDS: (60,16,16,8),(30,8,8,4),(15,4,4,2)
// IDX_MAX=(60,3,5) -> patch=(1,90,96); PADDING=(0,1,1) -> ppad=(1,92,98)
// t_embed: [64][1][92][98][14] = 8,078,336 f32 ; t_manip: [64][16]

#define N_PATCH 64
#define HALF_N 32
#define PPAD_H 92
#define PPAD_W 98
#define CH 14
#define PIX_PER_PATCH (PPAD_H * PPAD_W)        // 9016
#define ROWS_PER_BLOCK 2
#define BLOCKS_PER_PATCH 46                    // 46*2 = 92 rows
#define PX_PER_BLOCK 196                       // 2 rows * 98
#define F4_PER_BLOCK (PX_PER_BLOCK * CH / 4)   // 686
#define ELEMS_PER_PATCH (PIX_PER_PATCH * CH)   // 126224
#define ELEMS_PER_BLOCK (PX_PER_BLOCK * CH)    // 2744
#define TOTAL_EMBED (N_PATCH * ELEMS_PER_PATCH)
#define TOTAL_MANIP (N_PATCH * 16)

// per-row V-record layout (elements): L0 [0,48)=6cells*8ch, L1 [48,64)=4*4, L2 [64,70)=3*2
#define RB_STRIDE 72   // padded to keep rows 16B-aligned
#define L1_OFF 48
#define L2_OFF 64

__device__ __forceinline__ float lerpf(float a, float b, float f) {
    return a + f * (b - a);
}

// first (leftmost) clamped w-cell for this patch at a given level
__device__ __forceinline__ int wcell0(int rw0, float sw, int Wg) {
    float x = ((float)rw0 + 0.5f) * sw - 0.5f;
    int w0 = (int)floorf(x);
    return min(max(w0, 0), Wg - 1);
}

__global__ __launch_bounds__(256) void embed_kernel(
    const int* __restrict__ idx,
    const float* __restrict__ g0,
    const float* __restrict__ g1,
    const float* __restrict__ g2,
    float* __restrict__ out)
{
    __shared__ __align__(16) float s_V0[ROWS_PER_BLOCK * RB_STRIDE];   // 576 B
    __shared__ __align__(16) float s_V1[ROWS_PER_BLOCK * RB_STRIDE];   // 576 B
    __shared__ __align__(16) float s_buf0[PX_PER_BLOCK * CH];          // 11 KB
    __shared__ __align__(16) float s_buf1[PX_PER_BLOCK * CH];          // 11 KB

    const int tid = threadIdx.x;
    const int bx  = blockIdx.x;
    const int n0  = blockIdx.y;
    const int n1  = blockIdx.y + HALF_N;

    const float sw0 = (float)((double)16 / 480.0);
    const float sw1 = (float)((double)8  / 480.0);
    const float sw2 = (float)((double)4  / 480.0);
    const float sh0 = (float)((double)16 / 270.0);
    const float sh1 = (float)((double)8  / 270.0);
    const float sh2 = (float)((double)4  / 270.0);

    const int it0 = idx[3 * n0 + 0], ih0 = idx[3 * n0 + 1], iw0 = idx[3 * n0 + 2];
    const int it1 = idx[3 * n1 + 0], ih1 = idx[3 * n1 + 1], iw1 = idx[3 * n1 + 2];
    const int rw0a = iw0 * 96 - 1;
    const int rw0b = iw1 * 96 - 1;
    const int C00a = wcell0(rw0a, sw0, 16), C01a = wcell0(rw0a, sw1, 8), C02a = wcell0(rw0a, sw2, 4);
    const int C00b = wcell0(rw0b, sw0, 16), C01b = wcell0(rw0b, sw1, 8), C02b = wcell0(rw0b, sw2, 4);

    // ---- fused manip (one block only; reads idx of ALL patches) ----
    if (bx == 0 && blockIdx.y == 0) {
        float* om = out + TOTAL_EMBED;
        for (int e = tid; e < TOTAL_MANIP; e += 256) {
            int nn = e >> 4;
            int j  = e & 15;
            int l  = j & 7;
            float base = (float)M_PI * (float)(1 << l);  // fl32(2^l*pi), pow2 exact
            float v = (float)idx[3 * nn + 0] * base;     // f32 mul = reference
            double dv = (double)v;
            om[e] = (float)((j < 8) ? sin(dv) : cos(dv));
        }
    }

    // ---- build V tables for BOTH tiles in one gather phase (280 entries) ----
    for (int e = tid; e < 280; e += 256) {
        int t   = (e >= 140);
        int oa  = e - 140 * t;
        int row = (oa >= 70);
        int off = oa - 70 * row;
        int itq = t ? it1 : it0;
        int ihq = t ? ih1 : ih0;
        float* sV = t ? s_V1 : s_V0;
        int rh  = ihq * 90 + (bx * 2 + row) - 1;
        float mh = ((unsigned)rh < 270u) ? 1.0f : 0.0f;
        float v;
        if (off < L1_OFF) {
            // L0: 6 cells x 8 ch; T identity (t = itq exactly)
            int C00q = t ? C00b : C00a;
            int cell = off >> 3, chn = off & 7;
            float xh = ((float)rh + 0.5f) * sh0 - 0.5f;
            float ff = floorf(xh);
            float fh = xh - ff;
            int h0 = (int)ff;
            int h0c = min(max(h0, 0), 15), h1c = min(h0 + 1, 15);
            int cw = min(C00q + cell, 15);
            const float* base = g0 + (size_t)itq * 2048;
            float a = base[(h0c * 16 + cw) * 8 + chn];
            float b = base[(h1c * 16 + cw) * 8 + chn];
            v = mh * lerpf(a, b, fh);
        } else if (off < L2_OFF) {
            // L1: 4 cells x 4 ch; t-lerp + h-lerp
            int C01q = t ? C01b : C01a;
            int o = off - L1_OFF;
            int cell = o >> 2, chn = o & 3;
            float xh = ((float)rh + 0.5f) * sh1 - 0.5f;
            float ff = floorf(xh);
            float fh = xh - ff;
            int h0 = (int)ff;
            int h0c = min(max(h0, 0), 7), h1c = min(h0 + 1, 7);
            float xt = ((float)itq + 0.5f) * 0.5f - 0.5f;   // 30/60 exact
            float ftf = floorf(xt);
            float ft  = xt - ftf;
            int t0 = (int)ftf;
            int t0c = min(max(t0, 0), 29), t1c = min(t0 + 1, 29);
            int cw = min(C01q + cell, 7);
            float a00 = g1[((t0c * 8 + h0c) * 8 + cw) * 4 + chn];
            float a01 = g1[((t0c * 8 + h1c) * 8 + cw) * 4 + chn];
            float a10 = g1[((t1c * 8 + h0c) * 8 + cw) * 4 + chn];
            float a11 = g1[((t1c * 8 + h1c) * 8 + cw) * 4 + chn];
            v = mh * lerpf(lerpf(a00, a01, fh), lerpf(a10, a11, fh), ft);
        } else {
            // L2: 3 cells x 2 ch
            int C02q = t ? C02b : C02a;
            int o = off - L2_OFF;
            int cell = o >> 1, chn = o & 1;
            float xh = ((float)rh + 0.5f) * sh2 - 0.5f;
            float ff = floorf(xh);
            float fh = xh - ff;
            int h0 = (int)ff;
            int h0c = min(max(h0, 0), 3), h1c = min(h0 + 1, 3);
            float xt = ((float)itq + 0.5f) * 0.25f - 0.5f;  // 15/60 exact
            float ftf = floorf(xt);
            float ft  = xt - ftf;
            int t0 = (int)ftf;
            int t0c = min(max(t0, 0), 14), t1c = min(t0 + 1, 14);
            int cw = min(C02q + cell, 3);
            float a00 = g2[((t0c * 4 + h0c) * 4 + cw) * 2 + chn];
            float a01 = g2[((t0c * 4 + h1c) * 4 + cw) * 2 + chn];
            float a10 = g2[((t1c * 4 + h0c) * 4 + cw) * 2 + chn];
            float a11 = g2[((t1c * 4 + h1c) * 4 + cw) * 2 + chn];
            v = mh * lerpf(lerpf(a00, a01, fh), lerpf(a10, a11, fh), ft);
        }
        sV[row * RB_STRIDE + off] = v;
    }

    // per-pixel compute (identical arithmetic to R10), one tile
    auto compute_tile = [&](int iwq, int C00q, int C01q, int C02q,
                            const float* __restrict__ sV, float* __restrict__ sbuf) {
        if (tid >= PX_PER_BLOCK) return;
        int row = (tid >= PPAD_W);
        int ww  = tid - PPAD_W * row;
        int rw  = iwq * 96 + ww - 1;
        float mw = ((unsigned)rw < 480u) ? 1.0f : 0.0f;
        float rwc = (float)rw + 0.5f;

        float x0 = rwc * sw0 - 0.5f;
        float f0f = floorf(x0);
        float fw0 = x0 - f0f;
        int w00 = (int)f0f;
        int oA0 = (min(max(w00, 0), 15) - C00q) * 8;
        int oB0 = (min(w00 + 1, 15)    - C00q) * 8;
        float x1 = rwc * sw1 - 0.5f;
        float f1f = floorf(x1);
        float fw1 = x1 - f1f;
        int w01 = (int)f1f;
        int oA1 = L1_OFF + (min(max(w01, 0), 7) - C01q) * 4;
        int oB1 = L1_OFF + (min(w01 + 1, 7)     - C01q) * 4;
        float x2 = rwc * sw2 - 0.5f;
        float f2f = floorf(x2);
        float fw2 = x2 - f2f;
        int w02 = (int)f2f;
        int oA2 = L2_OFF + (min(max(w02, 0), 3) - C02q) * 2;
        int oB2 = L2_OFF + (min(w02 + 1, 3)     - C02q) * 2;

        const float* V = sV + row * RB_STRIDE;
        float4 A0  = *(const float4*)(V + oA0);
        float4 A1  = *(const float4*)(V + oA0 + 4);
        float4 B0  = *(const float4*)(V + oB0);
        float4 B1  = *(const float4*)(V + oB0 + 4);
        float4 C1a = *(const float4*)(V + oA1);
        float4 C1b = *(const float4*)(V + oB1);
        float2 C2a = *(const float2*)(V + oA2);
        float2 C2b = *(const float2*)(V + oB2);

        float2* b = (float2*)(sbuf + tid * CH);
        b[0] = make_float2(mw * lerpf(A0.x, B0.x, fw0),
                           mw * lerpf(A0.y, B0.y, fw0));
        b[1] = make_float2(mw * lerpf(A0.z, B0.z, fw0),
                           mw * lerpf(A0.w, B0.w, fw0));
        b[2] = make_float2(mw * lerpf(A1.x, B1.x, fw0),
                           mw * lerpf(A1.y, B1.y, fw0));
        b[3] = make_float2(mw * lerpf(A1.z, B1.z, fw0),
                           mw * lerpf(A1.w, B1.w, fw0));
        b[4] = make_float2(mw * lerpf(C1a.x, C1b.x, fw1),
                           mw * lerpf(C1a.y, C1b.y, fw1));
        b[5] = make_float2(mw * lerpf(C1a.z, C1b.z, fw1),
                           mw * lerpf(C1a.w, C1b.w, fw1));
        b[6] = make_float2(mw * lerpf(C2a.x, C2b.x, fw2),
                           mw * lerpf(C2a.y, C2b.y, fw2));
    };

    auto store_tile = [&](int nq, const float* __restrict__ sbuf) {
        const float4* sb = (const float4*)sbuf;
        float4* gb = (float4*)(out + (size_t)nq * ELEMS_PER_PATCH + bx * ELEMS_PER_BLOCK);
        for (int j = tid; j < F4_PER_BLOCK; j += 256) gb[j] = sb[j];
    };

    __syncthreads();                                   // V tables staged (both tiles)

    compute_tile(iw0, C00a, C01a, C02a, s_V0, s_buf0); // tile 0 -> s_buf0
    __syncthreads();

    store_tile(n0, s_buf0);                            // stores fly...
    compute_tile(iw1, C00b, C01b, C02b, s_V1, s_buf1); // ...while tile 1 computes
    __syncthreads();

    store_tile(n1, s_buf1);
}

extern "C" void kernel_launch(void* const* d_in, const int* in_sizes, int n_in,
                              void* d_out, int out_size, void* d_ws, size_t ws_size,
                              hipStream_t stream) {
    const int*   idx = (const int*)  d_in[0];
    const float* g0  = (const float*)d_in[3];
    const float* g1  = (const float*)d_in[4];
    const float* g2  = (const float*)d_in[5];
    float* out = (float*)d_out;

    dim3 grid(BLOCKS_PER_PATCH, HALF_N);   // (46, 32) = 1472 blocks, 2 patches each
    embed_kernel<<<grid, 256, 0, stream>>>(idx, g0, g1, g2, out);
}